// Round 1
// baseline (15207.613 us; speedup 1.0000x reference)
//
#include <hip/hip_runtime.h>

#define S_LEN 1024
#define BATCH 64
#define HIDDEN 512
#define NBLK 64            // 32 blocks layer-0 + 32 blocks layer-1
#define COLS_PER_BLK 16

typedef __attribute__((ext_vector_type(8))) short short8;   // 8 bf16 (4 VGPRs) MFMA frag
typedef __attribute__((ext_vector_type(4))) float f32x4;    // MFMA accumulator

__device__ __forceinline__ unsigned short f2bf(float x) {
  unsigned u = __builtin_bit_cast(unsigned, x);
  u += 0x7fffu + ((u >> 16) & 1u);          // round-to-nearest-even
  return (unsigned short)(u >> 16);
}
__device__ __forceinline__ float bf2f(unsigned short h) {
  unsigned u = ((unsigned)h) << 16;
  return __builtin_bit_cast(float, u);
}

// ws layout: [0,8KB) barrier counters (uint, one per iteration);
// then bf16 h-state buffers, each [2 parities][64][512] shorts:
//   h0_hi, h0_lo, h1_hi, h1_lo   (4 * 128 KB = 512 KB)
__global__ void k_init(unsigned* __restrict__ bar, int* __restrict__ hbufs) {
  int i = blockIdx.x * blockDim.x + threadIdx.x;
  if (i < 2048) bar[i] = 0u;
  for (int k = i; k < 131072; k += gridDim.x * blockDim.x) hbufs[k] = 0;
}

__launch_bounds__(256, 1)
__global__ void k_rnn(const int* __restrict__ x, const float* __restrict__ emb,
                      const float* __restrict__ Wih0, const float* __restrict__ b0,
                      const float* __restrict__ Whh0, const float* __restrict__ Wih1,
                      const float* __restrict__ b1, const float* __restrict__ Whh1,
                      float* __restrict__ out, unsigned* __restrict__ bar,
                      short* __restrict__ hbase) {
  // LDS: 4 fragment regions (ih_hi, ih_lo, hh_hi, hh_lo), each [16 kchunks][64 lanes][8 bf16]
  __shared__ short wlds[4 * 16 * 64 * 8];   // 64 KB

  const int tid  = threadIdx.x;
  const int wid  = tid >> 6;
  const int lane = tid & 63;
  const int bx   = blockIdx.x;
  const int layer = bx >> 5;                 // 0 or 1
  const int cg    = bx & 31;
  const int col0  = cg * COLS_PER_BLK;

  const float* Wih  = layer ? Wih1 : Wih0;   // [512][512] row-major (k, col)
  const float* Whh  = layer ? Whh1 : Whh0;
  const float* bias = layer ? b1   : b0;

  // ---- stage W column-slices into LDS as pre-packed MFMA B-fragments (hi/lo bf16) ----
  {
    const int c = col0 + (lane & 15);
    for (int kc = wid; kc < 16; kc += 4) {
      const int k0 = kc * 32 + (lane >> 4) * 8;
      const int basei = (kc * 64 + lane) * 8;
      #pragma unroll
      for (int j = 0; j < 8; ++j) {
        float v = Wih[(size_t)(k0 + j) * HIDDEN + c];
        unsigned short vh = f2bf(v);
        wlds[0 * 8192 + basei + j] = (short)vh;
        wlds[1 * 8192 + basei + j] = (short)f2bf(v - bf2f(vh));
        float w = Whh[(size_t)(k0 + j) * HIDDEN + c];
        unsigned short wh = f2bf(w);
        wlds[2 * 8192 + basei + j] = (short)wh;
        wlds[3 * 8192 + basei + j] = (short)f2bf(w - bf2f(wh));
      }
    }
  }
  __syncthreads();

  short* h0_hi = hbase;                       // [2][64*512]
  short* h0_lo = hbase + 65536;
  short* h1_hi = hbase + 131072;
  short* h1_lo = hbase + 196608;

  const int arow  = wid * 16 + (lane & 15);   // A-fragment row = batch index
  const int kgo   = (lane >> 4) * 8;          // k offset inside a 32-chunk
  const int ccol  = col0 + (lane & 15);       // D col (m89-verified C/D map)
  const int drow0 = wid * 16 + (lane >> 4) * 4; // D row base
  const float bc  = bias[ccol];

  float* out_seq = out;                               // [64][1024][512]
  float* hidden  = out + (size_t)BATCH * S_LEN * HIDDEN; // [2][64][512]

  for (int i = 0; i <= S_LEN; ++i) {
    const int p  = i & 1;
    const int wp = p ^ 1;

    if (layer == 0) {
      if (i < S_LEN) {
        // h0_i = tanh(emb[x[:,i]] @ Wih0 + b0 + h0_{i-1} @ Whh0)
        const int xr = x[arow * S_LEN + i];
        const float* erow = emb + (size_t)xr * HIDDEN;
        const short* hh_p = h0_hi + p * 32768 + arow * HIDDEN;
        const short* hl_p = h0_lo + p * 32768 + arow * HIDDEN;
        f32x4 acc = {bc, bc, bc, bc};
        #pragma unroll
        for (int kc = 0; kc < 16; ++kc) {
          const int ko = kc * 32 + kgo;
          const float4* ep = (const float4*)(erow + ko);
          float4 e0 = ep[0], e1 = ep[1];
          short8 ea;
          ea[0] = (short)f2bf(e0.x); ea[1] = (short)f2bf(e0.y);
          ea[2] = (short)f2bf(e0.z); ea[3] = (short)f2bf(e0.w);
          ea[4] = (short)f2bf(e1.x); ea[5] = (short)f2bf(e1.y);
          ea[6] = (short)f2bf(e1.z); ea[7] = (short)f2bf(e1.w);
          short8 ha = *(const short8*)(hh_p + ko);
          short8 la = *(const short8*)(hl_p + ko);
          const int fb = (kc * 64 + lane) * 8;
          short8 wih_h = *(const short8*)&wlds[0 * 8192 + fb];
          short8 wih_l = *(const short8*)&wlds[1 * 8192 + fb];
          short8 whh_h = *(const short8*)&wlds[2 * 8192 + fb];
          short8 whh_l = *(const short8*)&wlds[3 * 8192 + fb];
          acc = __builtin_amdgcn_mfma_f32_16x16x32_bf16(ea, wih_h, acc, 0, 0, 0);
          acc = __builtin_amdgcn_mfma_f32_16x16x32_bf16(ea, wih_l, acc, 0, 0, 0);
          acc = __builtin_amdgcn_mfma_f32_16x16x32_bf16(ha, whh_h, acc, 0, 0, 0);
          acc = __builtin_amdgcn_mfma_f32_16x16x32_bf16(ha, whh_l, acc, 0, 0, 0);
          acc = __builtin_amdgcn_mfma_f32_16x16x32_bf16(la, whh_h, acc, 0, 0, 0);
        }
        #pragma unroll
        for (int j = 0; j < 4; ++j) {
          const int r = drow0 + j;
          float hv = tanhf(acc[j]);
          unsigned short hi = f2bf(hv);
          unsigned short lo = f2bf(hv - bf2f(hi));
          h0_hi[wp * 32768 + r * HIDDEN + ccol] = (short)hi;
          h0_lo[wp * 32768 + r * HIDDEN + ccol] = (short)lo;
          if (i == S_LEN - 1) hidden[r * HIDDEN + ccol] = hv;   // hidden[0]
        }
      }
    } else {
      if (i >= 1) {
        // h1_{i-1} = tanh(h0_{i-1} @ Wih1 + b1 + h1_{i-2} @ Whh1)
        const short* a_hh = h0_hi + p  * 32768 + arow * HIDDEN;  // h0_{i-1}
        const short* a_hl = h0_lo + p  * 32768 + arow * HIDDEN;
        const short* c_hh = h1_hi + wp * 32768 + arow * HIDDEN;  // h1_{i-2}
        const short* c_hl = h1_lo + wp * 32768 + arow * HIDDEN;
        f32x4 acc = {bc, bc, bc, bc};
        #pragma unroll
        for (int kc = 0; kc < 16; ++kc) {
          const int ko = kc * 32 + kgo;
          short8 ah = *(const short8*)(a_hh + ko);
          short8 al = *(const short8*)(a_hl + ko);
          short8 ch = *(const short8*)(c_hh + ko);
          short8 cl = *(const short8*)(c_hl + ko);
          const int fb = (kc * 64 + lane) * 8;
          short8 wih_h = *(const short8*)&wlds[0 * 8192 + fb];
          short8 wih_l = *(const short8*)&wlds[1 * 8192 + fb];
          short8 whh_h = *(const short8*)&wlds[2 * 8192 + fb];
          short8 whh_l = *(const short8*)&wlds[3 * 8192 + fb];
          acc = __builtin_amdgcn_mfma_f32_16x16x32_bf16(ah, wih_h, acc, 0, 0, 0);
          acc = __builtin_amdgcn_mfma_f32_16x16x32_bf16(ah, wih_l, acc, 0, 0, 0);
          acc = __builtin_amdgcn_mfma_f32_16x16x32_bf16(al, wih_h, acc, 0, 0, 0);
          acc = __builtin_amdgcn_mfma_f32_16x16x32_bf16(ch, whh_h, acc, 0, 0, 0);
          acc = __builtin_amdgcn_mfma_f32_16x16x32_bf16(ch, whh_l, acc, 0, 0, 0);
          acc = __builtin_amdgcn_mfma_f32_16x16x32_bf16(cl, whh_h, acc, 0, 0, 0);
        }
        const int t = i - 1;
        #pragma unroll
        for (int j = 0; j < 4; ++j) {
          const int r = drow0 + j;
          float hv = tanhf(acc[j]);
          unsigned short hi = f2bf(hv);
          unsigned short lo = f2bf(hv - bf2f(hi));
          h1_hi[p * 32768 + r * HIDDEN + ccol] = (short)hi;
          h1_lo[p * 32768 + r * HIDDEN + ccol] = (short)lo;
          out_seq[(size_t)r * S_LEN * HIDDEN + (size_t)t * HIDDEN + ccol] = hv;
          if (i == S_LEN) hidden[32768 + r * HIDDEN + ccol] = hv;  // hidden[1]
        }
      }
    }

    // device-scope barrier i (one fresh counter per iteration; skipped after last)
    if (i < S_LEN) {
      __syncthreads();                       // drains this block's stores (vmcnt(0) before s_barrier)
      if (tid == 0) {
        __threadfence();                     // release: make h stores agent-visible
        __hip_atomic_fetch_add(&bar[i], 1u, __ATOMIC_RELAXED, __HIP_MEMORY_SCOPE_AGENT);
        while (__hip_atomic_load(&bar[i], __ATOMIC_ACQUIRE, __HIP_MEMORY_SCOPE_AGENT) < NBLK) {
          __builtin_amdgcn_s_sleep(2);
        }
        __threadfence();                     // acquire: invalidate stale L1/L2 lines
      }
      __syncthreads();
    }
  }
}

extern "C" void kernel_launch(void* const* d_in, const int* in_sizes, int n_in,
                              void* d_out, int out_size, void* d_ws, size_t ws_size,
                              hipStream_t stream) {
  const int*   x    = (const int*)d_in[0];
  // d_in[1] = lengths : unused by the reference
  const float* emb  = (const float*)d_in[2];
  const float* Wih0 = (const float*)d_in[3];
  const float* b0   = (const float*)d_in[4];
  const float* Whh0 = (const float*)d_in[5];
  const float* Wih1 = (const float*)d_in[6];
  const float* b1   = (const float*)d_in[7];
  const float* Whh1 = (const float*)d_in[8];
  float* out = (float*)d_out;

  unsigned* bar   = (unsigned*)d_ws;
  short*    hbase = (short*)((char*)d_ws + 8192);

  // re-zero barrier counters + initial h-state every call (ws is not re-poisoned between replays)
  k_init<<<256, 256, 0, stream>>>(bar, (int*)hbase);
  k_rnn<<<NBLK, 256, 0, stream>>>(x, emb, Wih0, b0, Whh0, Wih1, b1, Whh1, out, bar, hbase);
}

// Round 2
// 11259.234 us; speedup vs baseline: 1.3507x; 1.3507x over previous
//
#include <hip/hip_runtime.h>

#define S_LEN 1024
#define BATCH 64
#define HIDDEN 512
#define NBLK 64            // 32 blocks layer-0 + 32 blocks layer-1
#define COLS_PER_BLK 16

typedef __attribute__((ext_vector_type(8))) short short8;   // 8 bf16 (4 VGPRs) MFMA frag
typedef __attribute__((ext_vector_type(4))) float f32x4;    // MFMA accumulator

__device__ __forceinline__ unsigned short f2bf(float x) {
  unsigned u = __builtin_bit_cast(unsigned, x);
  u += 0x7fffu + ((u >> 16) & 1u);          // round-to-nearest-even
  return (unsigned short)(u >> 16);
}
__device__ __forceinline__ float bf2f(unsigned short h) {
  unsigned u = ((unsigned)h) << 16;
  return __builtin_bit_cast(float, u);
}

// device-scope write-through 2B store (lands at coherence point; no dirty L2 line)
__device__ __forceinline__ void st_h2(short* p, unsigned short v) {
  asm volatile("global_store_short %0, %1, off sc1" :: "v"(p), "v"((unsigned)v) : "memory");
}

// fragment load: two relaxed agent (sc1) 8B atomic loads -> 16B MFMA A-fragment.
// Relaxed agent atomic loads read the coherence point (bypass stale L1/L2) with
// NO buffer_inv, and the compiler schedules/batches their vmcnt normally.
__device__ __forceinline__ short8 ld_frag(const unsigned long long* p) {
  union { unsigned long long q[2]; short8 s; } u;
  u.q[0] = __hip_atomic_load(p,     __ATOMIC_RELAXED, __HIP_MEMORY_SCOPE_AGENT);
  u.q[1] = __hip_atomic_load(p + 1, __ATOMIC_RELAXED, __HIP_MEMORY_SCOPE_AGENT);
  return u.s;
}

// h state layout: MFMA-A-fragment packed, [parity][wid][kc][lane][8] bf16 shorts.
// One wave's per-kc fragment = contiguous 1KB -> fully coalesced at the L2-bypass path.
#define HOFF(p, w, kc, l) ((((((p) * 4 + (w)) * 16 + (kc)) * 64 + (l))) * 8)

// ws layout: [0,8KB) barrier counters (uint, one per iteration);
// then 4 packed h buffers (h0_hi, h0_lo, h1_hi, h1_lo), each [2][4][16][64][8] shorts = 128KB.
__global__ void k_init(unsigned* __restrict__ bar, int* __restrict__ hbufs) {
  int i = blockIdx.x * blockDim.x + threadIdx.x;
  if (i < 2048) bar[i] = 0u;
  for (int k = i; k < 131072; k += gridDim.x * blockDim.x) hbufs[k] = 0;
}

__launch_bounds__(256, 1)
__global__ void k_rnn(const int* __restrict__ x, const float* __restrict__ emb,
                      const float* __restrict__ Wih0, const float* __restrict__ b0,
                      const float* __restrict__ Whh0, const float* __restrict__ Wih1,
                      const float* __restrict__ b1, const float* __restrict__ Whh1,
                      float* __restrict__ out, unsigned* __restrict__ bar,
                      short* __restrict__ hbase) {
  // LDS: 4 fragment regions (ih_hi, ih_lo, hh_hi, hh_lo), each [16 kchunks][64 lanes][8 bf16]
  __shared__ short wlds[4 * 16 * 64 * 8];   // 64 KB

  const int tid  = threadIdx.x;
  const int wid  = tid >> 6;
  const int lane = tid & 63;
  const int bx   = blockIdx.x;
  const int layer = bx >> 5;                 // 0 or 1
  const int cg    = bx & 31;
  const int col0  = cg * COLS_PER_BLK;

  const float* Wih  = layer ? Wih1 : Wih0;   // [512][512] row-major (k, col)
  const float* Whh  = layer ? Whh1 : Whh0;
  const float* bias = layer ? b1   : b0;

  // ---- stage W column-slices into LDS as pre-packed MFMA B-fragments (hi/lo bf16) ----
  {
    const int c = col0 + (lane & 15);
    for (int kc = wid; kc < 16; kc += 4) {
      const int k0 = kc * 32 + (lane >> 4) * 8;
      const int basei = (kc * 64 + lane) * 8;
      #pragma unroll
      for (int j = 0; j < 8; ++j) {
        float v = Wih[(size_t)(k0 + j) * HIDDEN + c];
        unsigned short vh = f2bf(v);
        wlds[0 * 8192 + basei + j] = (short)vh;
        wlds[1 * 8192 + basei + j] = (short)f2bf(v - bf2f(vh));
        float w = Whh[(size_t)(k0 + j) * HIDDEN + c];
        unsigned short wh = f2bf(w);
        wlds[2 * 8192 + basei + j] = (short)wh;
        wlds[3 * 8192 + basei + j] = (short)f2bf(w - bf2f(wh));
      }
    }
  }
  __syncthreads();

  short* h0_hi = hbase;                       // packed, 65536 shorts each
  short* h0_lo = hbase + 65536;
  short* h1_hi = hbase + 131072;
  short* h1_lo = hbase + 196608;
  const unsigned long long* h0_hi64 = (const unsigned long long*)h0_hi;
  const unsigned long long* h0_lo64 = (const unsigned long long*)h0_lo;
  const unsigned long long* h1_hi64 = (const unsigned long long*)h1_hi;
  const unsigned long long* h1_lo64 = (const unsigned long long*)h1_lo;

  const int arow  = wid * 16 + (lane & 15);   // A-fragment row = batch index
  const int ccol  = col0 + (lane & 15);       // D col (m89-verified C/D map)
  const int drow0 = wid * 16 + (lane >> 4) * 4; // D row base
  const float bc  = bias[ccol];

  // packed-layout store coords for this thread's output column ccol:
  const int skc  = ccol >> 5;                 // kc of the k-index ccol
  const int ssub = (ccol & 31) >> 3;          // which 8-wide k-subchunk
  const int sj   = ccol & 7;                  // position within subchunk
  // store lane for row r: (r&15) + 16*ssub ; r>>4 == wid (rows stay in own wid band)

  float* out_seq = out;                               // [64][1024][512]
  float* hidden  = out + (size_t)BATCH * S_LEN * HIDDEN; // [2][64][512]

  for (int i = 0; i <= S_LEN; ++i) {
    const int p  = i & 1;
    const int wp = p ^ 1;

    if (layer == 0) {
      if (i < S_LEN) {
        // h0_i = tanh(emb[x[:,i]] @ Wih0 + b0 + h0_{i-1} @ Whh0)
        const int xr = x[arow * S_LEN + i];
        const float* erow = emb + (size_t)xr * HIDDEN;
        f32x4 acc = {bc, bc, bc, bc};
        #pragma unroll
        for (int kc = 0; kc < 16; ++kc) {
          const int ko = kc * 32 + (lane >> 4) * 8;
          const float4* ep = (const float4*)(erow + ko);
          float4 e0 = ep[0], e1 = ep[1];
          short8 ea;
          ea[0] = (short)f2bf(e0.x); ea[1] = (short)f2bf(e0.y);
          ea[2] = (short)f2bf(e0.z); ea[3] = (short)f2bf(e0.w);
          ea[4] = (short)f2bf(e1.x); ea[5] = (short)f2bf(e1.y);
          ea[6] = (short)f2bf(e1.z); ea[7] = (short)f2bf(e1.w);
          const int hoff = HOFF(p, wid, kc, lane) >> 2;   // u64 index
          short8 ha = ld_frag(h0_hi64 + hoff);
          short8 la = ld_frag(h0_lo64 + hoff);
          const int fb = (kc * 64 + lane) * 8;
          short8 wih_h = *(const short8*)&wlds[0 * 8192 + fb];
          short8 wih_l = *(const short8*)&wlds[1 * 8192 + fb];
          short8 whh_h = *(const short8*)&wlds[2 * 8192 + fb];
          short8 whh_l = *(const short8*)&wlds[3 * 8192 + fb];
          acc = __builtin_amdgcn_mfma_f32_16x16x32_bf16(ea, wih_h, acc, 0, 0, 0);
          acc = __builtin_amdgcn_mfma_f32_16x16x32_bf16(ea, wih_l, acc, 0, 0, 0);
          acc = __builtin_amdgcn_mfma_f32_16x16x32_bf16(ha, whh_h, acc, 0, 0, 0);
          acc = __builtin_amdgcn_mfma_f32_16x16x32_bf16(ha, whh_l, acc, 0, 0, 0);
          acc = __builtin_amdgcn_mfma_f32_16x16x32_bf16(la, whh_h, acc, 0, 0, 0);
        }
        #pragma unroll
        for (int j = 0; j < 4; ++j) {
          const int r = drow0 + j;
          float hv = tanhf(acc[j]);
          unsigned short hi = f2bf(hv);
          unsigned short lo = f2bf(hv - bf2f(hi));
          const int so = HOFF(wp, wid, skc, (r & 15) + 16 * ssub) + sj;
          st_h2(h0_hi + so, hi);
          st_h2(h0_lo + so, lo);
          if (i == S_LEN - 1) hidden[r * HIDDEN + ccol] = hv;   // hidden[0]
        }
      }
    } else {
      if (i >= 1) {
        // h1_{i-1} = tanh(h0_{i-1} @ Wih1 + b1 + h1_{i-2} @ Whh1)
        f32x4 acc = {bc, bc, bc, bc};
        #pragma unroll
        for (int kc = 0; kc < 16; ++kc) {
          const int hoff_a = HOFF(p,  wid, kc, lane) >> 2;  // h0_{i-1}
          const int hoff_c = HOFF(wp, wid, kc, lane) >> 2;  // h1_{i-2}
          short8 ah = ld_frag(h0_hi64 + hoff_a);
          short8 al = ld_frag(h0_lo64 + hoff_a);
          short8 ch = ld_frag(h1_hi64 + hoff_c);
          short8 cl = ld_frag(h1_lo64 + hoff_c);
          const int fb = (kc * 64 + lane) * 8;
          short8 wih_h = *(const short8*)&wlds[0 * 8192 + fb];
          short8 wih_l = *(const short8*)&wlds[1 * 8192 + fb];
          short8 whh_h = *(const short8*)&wlds[2 * 8192 + fb];
          short8 whh_l = *(const short8*)&wlds[3 * 8192 + fb];
          acc = __builtin_amdgcn_mfma_f32_16x16x32_bf16(ah, wih_h, acc, 0, 0, 0);
          acc = __builtin_amdgcn_mfma_f32_16x16x32_bf16(ah, wih_l, acc, 0, 0, 0);
          acc = __builtin_amdgcn_mfma_f32_16x16x32_bf16(al, wih_h, acc, 0, 0, 0);
          acc = __builtin_amdgcn_mfma_f32_16x16x32_bf16(ch, whh_h, acc, 0, 0, 0);
          acc = __builtin_amdgcn_mfma_f32_16x16x32_bf16(ch, whh_l, acc, 0, 0, 0);
          acc = __builtin_amdgcn_mfma_f32_16x16x32_bf16(cl, whh_h, acc, 0, 0, 0);
        }
        const int t = i - 1;
        #pragma unroll
        for (int j = 0; j < 4; ++j) {
          const int r = drow0 + j;
          float hv = tanhf(acc[j]);
          unsigned short hi = f2bf(hv);
          unsigned short lo = f2bf(hv - bf2f(hi));
          const int so = HOFF(p, wid, skc, (r & 15) + 16 * ssub) + sj;
          st_h2(h1_hi + so, hi);
          st_h2(h1_lo + so, lo);
          out_seq[(size_t)r * S_LEN * HIDDEN + (size_t)t * HIDDEN + ccol] = hv;
          if (i == S_LEN) hidden[32768 + r * HIDDEN + ccol] = hv;  // hidden[1]
        }
      }
    }

    // device-scope barrier i — NO cache-maintenance fences:
    // write-through (sc1) h stores retire at vmcnt(0) => globally visible;
    // readers use sc1 loads => no buffer_inv needed.
    if (i < S_LEN) {
      asm volatile("s_waitcnt vmcnt(0)" ::: "memory");  // drain this wave's h stores to CP
      __syncthreads();                                  // all waves drained before arrival
      if (tid == 0)
        __hip_atomic_fetch_add(&bar[i], 1u, __ATOMIC_RELAXED, __HIP_MEMORY_SCOPE_AGENT);
      // all lanes spin (same address -> one broadcast request per poll); each wave
      // exits as soon as it observes completion — no exit __syncthreads needed.
      while (__hip_atomic_load(&bar[i], __ATOMIC_RELAXED, __HIP_MEMORY_SCOPE_AGENT) < NBLK)
        __builtin_amdgcn_s_sleep(1);
      asm volatile("" ::: "memory");                    // compiler fence: no hoisting past spin
    }
  }
}

extern "C" void kernel_launch(void* const* d_in, const int* in_sizes, int n_in,
                              void* d_out, int out_size, void* d_ws, size_t ws_size,
                              hipStream_t stream) {
  const int*   x    = (const int*)d_in[0];
  // d_in[1] = lengths : unused by the reference
  const float* emb  = (const float*)d_in[2];
  const float* Wih0 = (const float*)d_in[3];
  const float* b0   = (const float*)d_in[4];
  const float* Whh0 = (const float*)d_in[5];
  const float* Wih1 = (const float*)d_in[6];
  const float* b1   = (const float*)d_in[7];
  const float* Whh1 = (const float*)d_in[8];
  float* out = (float*)d_out;

  unsigned* bar   = (unsigned*)d_ws;
  short*    hbase = (short*)((char*)d_ws + 8192);

  // re-zero barrier counters + initial h-state every call (ws is not re-poisoned
  // between replays; k_init's kernel-end flush makes the zeros visible at the CP)
  k_init<<<256, 256, 0, stream>>>(bar, (int*)hbase);
  k_rnn<<<NBLK, 256, 0, stream>>>(x, emb, Wih0, b0, Whh0, Wih1, b1, Whh1, out, bar, hbase);
}

// Round 3
// 10143.771 us; speedup vs baseline: 1.4992x; 1.1100x over previous
//
#include <hip/hip_runtime.h>

#define S_LEN 1024
#define BATCH 64
#define HIDDEN 512
#define NBLK 64            // 32 blocks layer-0 + 32 blocks layer-1
#define COLS_PER_BLK 16

typedef __attribute__((ext_vector_type(8))) short short8;   // 8 bf16 (4 VGPRs) MFMA frag
typedef __attribute__((ext_vector_type(4))) float f32x4;    // MFMA accumulator
typedef __attribute__((ext_vector_type(4))) unsigned int u32x4;

__device__ __forceinline__ unsigned short f2bf(float x) {
  unsigned u = __builtin_bit_cast(unsigned, x);
  u += 0x7fffu + ((u >> 16) & 1u);          // round-to-nearest-even
  return (unsigned short)(u >> 16);
}
__device__ __forceinline__ float bf2f(unsigned short h) {
  unsigned u = ((unsigned)h) << 16;
  return __builtin_bit_cast(float, u);
}

// device-scope write-through 16B store (lands at coherence point; no dirty L2 line)
__device__ __forceinline__ void st16_sc1(void* p, u32x4 v) {
  asm volatile("global_store_dwordx4 %0, %1, off sc1" :: "v"(p), "v"(v) : "memory");
}

// fragment load: two relaxed agent (sc1) 8B atomic loads -> 16B MFMA A-fragment.
__device__ __forceinline__ short8 ld_frag(const unsigned long long* p) {
  union { unsigned long long q[2]; short8 s; } u;
  u.q[0] = __hip_atomic_load(p,     __ATOMIC_RELAXED, __HIP_MEMORY_SCOPE_AGENT);
  u.q[1] = __hip_atomic_load(p + 1, __ATOMIC_RELAXED, __HIP_MEMORY_SCOPE_AGENT);
  return u.s;
}

// h state layout: MFMA-A-fragment packed, [parity][wid][kc][lane][8] bf16 shorts.
#define HOFF(p, w, kc, l) ((((((p) * 4 + (w)) * 16 + (kc)) * 64 + (l))) * 8)

// ws layout: [0,1KB) arrival-tag flags (uint, stride 2, one slot per block);
// then 4 packed h buffers (h0_hi, h0_lo, h1_hi, h1_lo), each 65536 shorts = 128KB.
__global__ void k_init(unsigned* __restrict__ flags, int* __restrict__ hbufs) {
  int i = blockIdx.x * blockDim.x + threadIdx.x;
  if (i < 256) flags[i] = 0u;
  for (int k = i; k < 131072; k += gridDim.x * blockDim.x) hbufs[k] = 0;
}

__launch_bounds__(256, 1)
__global__ void k_rnn(const int* __restrict__ x, const float* __restrict__ emb,
                      const float* __restrict__ Wih0, const float* __restrict__ b0,
                      const float* __restrict__ Whh0, const float* __restrict__ Wih1,
                      const float* __restrict__ b1, const float* __restrict__ Whh1,
                      float* __restrict__ out, unsigned* __restrict__ flags,
                      short* __restrict__ hbase) {
  // LDS: 4 W-fragment regions (ih_hi, ih_lo, hh_hi, hh_lo), each [16 kc][64 lanes][8]
  __shared__ short wlds[4 * 16 * 64 * 8];                 // 64 KB
  __shared__ __align__(16) short stage[2][4][32][8];      // 4 KB publication staging

  const int tid  = threadIdx.x;
  const int wid  = tid >> 6;
  const int lane = tid & 63;
  const int bx   = blockIdx.x;
  const int layer = bx >> 5;                 // 0 or 1
  const int cg    = bx & 31;
  const int col0  = cg * COLS_PER_BLK;

  const float* Wih  = layer ? Wih1 : Wih0;   // [512][512] row-major (k, col)
  const float* Whh  = layer ? Whh1 : Whh0;
  const float* bias = layer ? b1   : b0;

  // ---- stage W column-slices into LDS as pre-packed MFMA B-fragments (hi/lo bf16) ----
  {
    const int c = col0 + (lane & 15);
    for (int kc = wid; kc < 16; kc += 4) {
      const int k0 = kc * 32 + (lane >> 4) * 8;
      const int basei = (kc * 64 + lane) * 8;
      #pragma unroll
      for (int j = 0; j < 8; ++j) {
        float v = Wih[(size_t)(k0 + j) * HIDDEN + c];
        unsigned short vh = f2bf(v);
        wlds[0 * 8192 + basei + j] = (short)vh;
        wlds[1 * 8192 + basei + j] = (short)f2bf(v - bf2f(vh));
        float w = Whh[(size_t)(k0 + j) * HIDDEN + c];
        unsigned short wh = f2bf(w);
        wlds[2 * 8192 + basei + j] = (short)wh;
        wlds[3 * 8192 + basei + j] = (short)f2bf(w - bf2f(wh));
      }
    }
  }
  __syncthreads();

  short* h0_hi = hbase;                       // packed, 65536 shorts each
  short* h0_lo = hbase + 65536;
  short* h1_hi = hbase + 131072;
  short* h1_lo = hbase + 196608;
  const unsigned long long* h0_hi64 = (const unsigned long long*)h0_hi;
  const unsigned long long* h0_lo64 = (const unsigned long long*)h0_lo;
  const unsigned long long* h1_hi64 = (const unsigned long long*)h1_hi;
  const unsigned long long* h1_lo64 = (const unsigned long long*)h1_lo;
  short* hL_hi = layer ? h1_hi : h0_hi;       // this block's output buffers
  short* hL_lo = layer ? h1_lo : h0_lo;

  const int arow  = wid * 16 + (lane & 15);   // A-fragment row = batch index
  const int kgo   = (lane >> 4) * 8;          // k offset inside a 32-chunk
  const int ccol  = col0 + (lane & 15);       // D col (m89-verified C/D map)
  const int drow0 = wid * 16 + (lane >> 4) * 4; // D row base
  const float bc  = bias[ccol];

  // publication coords: ccol maps to packed (skc, lane-slot, j)
  const int skc   = ccol >> 5;
  const int sub0  = (cg & 1) * 2;                    // block's 32-lane window start /16
  const int slotb = (lane >> 4) * 4 + 16 * ((lane & 15) >> 3);  // + j = local slot
  const int sjj   = lane & 7;

  float* out_seq = out;                                  // [64][1024][512]
  float* hidden  = out + (size_t)BATCH * S_LEN * HIDDEN; // [2][64][512]

  short8 ea_reg[16];
  #define LOAD_EA(t) do {                                                   \
    const int xr_ = x[arow * S_LEN + (t)];                                  \
    const float* erow_ = emb + (size_t)xr_ * HIDDEN;                        \
    _Pragma("unroll")                                                       \
    for (int kc = 0; kc < 16; ++kc) {                                       \
      const float4* ep_ = (const float4*)(erow_ + kc * 32 + kgo);           \
      float4 e0_ = ep_[0], e1_ = ep_[1];                                    \
      short8 ea_;                                                           \
      ea_[0] = (short)f2bf(e0_.x); ea_[1] = (short)f2bf(e0_.y);             \
      ea_[2] = (short)f2bf(e0_.z); ea_[3] = (short)f2bf(e0_.w);             \
      ea_[4] = (short)f2bf(e1_.x); ea_[5] = (short)f2bf(e1_.y);             \
      ea_[6] = (short)f2bf(e1_.z); ea_[7] = (short)f2bf(e1_.w);             \
      ea_reg[kc] = ea_;                                                     \
    } } while (0)

  if (layer == 0) LOAD_EA(0);

  for (int i = 0; i <= S_LEN; ++i) {
    const int p  = i & 1;
    const int wp = p ^ 1;

    if (layer == 0) {
      if (i < S_LEN) {
        // h0_i = tanh(emb[x[:,i]] @ Wih0 + b0 + h0_{i-1} @ Whh0)
        f32x4 acc0 = {bc, bc, bc, bc};
        f32x4 acc1 = {0.f, 0.f, 0.f, 0.f};
        #pragma unroll
        for (int kc = 0; kc < 16; ++kc) {
          const int hoff = HOFF(p, wid, kc, lane) >> 2;   // u64 index
          short8 ha = ld_frag(h0_hi64 + hoff);
          short8 la = ld_frag(h0_lo64 + hoff);
          const int fb = (kc * 64 + lane) * 8;
          short8 wih_h = *(const short8*)&wlds[0 * 8192 + fb];
          short8 wih_l = *(const short8*)&wlds[1 * 8192 + fb];
          short8 whh_h = *(const short8*)&wlds[2 * 8192 + fb];
          short8 whh_l = *(const short8*)&wlds[3 * 8192 + fb];
          f32x4& ac = (kc & 1) ? acc1 : acc0;
          ac = __builtin_amdgcn_mfma_f32_16x16x32_bf16(ea_reg[kc], wih_h, ac, 0, 0, 0);
          ac = __builtin_amdgcn_mfma_f32_16x16x32_bf16(ea_reg[kc], wih_l, ac, 0, 0, 0);
          ac = __builtin_amdgcn_mfma_f32_16x16x32_bf16(ha, whh_h, ac, 0, 0, 0);
          ac = __builtin_amdgcn_mfma_f32_16x16x32_bf16(ha, whh_l, ac, 0, 0, 0);
          ac = __builtin_amdgcn_mfma_f32_16x16x32_bf16(la, whh_h, ac, 0, 0, 0);
        }
        #pragma unroll
        for (int j = 0; j < 4; ++j) {
          const int r = drow0 + j;
          float hv = tanhf(acc0[j] + acc1[j]);
          unsigned short hi = f2bf(hv);
          unsigned short lo = f2bf(hv - bf2f(hi));
          stage[0][wid][slotb + j][sjj] = (short)hi;
          stage[1][wid][slotb + j][sjj] = (short)lo;
          if (i == S_LEN - 1) hidden[r * HIDDEN + ccol] = hv;   // hidden[0]
        }
        // intra-wave publication: LDS transpose -> one coalesced 16B sc1 store/thread
        asm volatile("s_waitcnt lgkmcnt(0)" ::: "memory");
        {
          const int l2 = lane & 31, sel = lane >> 5;
          u32x4 v = *(const u32x4*)&stage[sel][wid][l2][0];
          short* dst = (sel ? hL_lo : hL_hi) +
                       (((wp * 4 + wid) * 16 + skc) * 64 + sub0 * 16 + l2) * 8;
          st16_sc1(dst, v);
        }
        if (i + 1 < S_LEN) LOAD_EA(i + 1);   // prefetch next emb (pre-barrier)
      }
    } else {
      if (i >= 1) {
        // h1_{i-1} = tanh(h0_{i-1} @ Wih1 + b1 + h1_{i-2} @ Whh1)
        f32x4 acc0 = {bc, bc, bc, bc};
        f32x4 acc1 = {0.f, 0.f, 0.f, 0.f};
        #pragma unroll
        for (int kc = 0; kc < 16; ++kc) {
          const int hoff_a = HOFF(p,  wid, kc, lane) >> 2;  // h0_{i-1}
          const int hoff_c = HOFF(wp, wid, kc, lane) >> 2;  // h1_{i-2}
          short8 ah = ld_frag(h0_hi64 + hoff_a);
          short8 al = ld_frag(h0_lo64 + hoff_a);
          short8 ch = ld_frag(h1_hi64 + hoff_c);
          short8 cl = ld_frag(h1_lo64 + hoff_c);
          const int fb = (kc * 64 + lane) * 8;
          short8 wih_h = *(const short8*)&wlds[0 * 8192 + fb];
          short8 wih_l = *(const short8*)&wlds[1 * 8192 + fb];
          short8 whh_h = *(const short8*)&wlds[2 * 8192 + fb];
          short8 whh_l = *(const short8*)&wlds[3 * 8192 + fb];
          f32x4& ac = (kc & 1) ? acc1 : acc0;
          ac = __builtin_amdgcn_mfma_f32_16x16x32_bf16(ah, wih_h, ac, 0, 0, 0);
          ac = __builtin_amdgcn_mfma_f32_16x16x32_bf16(ah, wih_l, ac, 0, 0, 0);
          ac = __builtin_amdgcn_mfma_f32_16x16x32_bf16(al, wih_h, ac, 0, 0, 0);
          ac = __builtin_amdgcn_mfma_f32_16x16x32_bf16(ch, whh_h, ac, 0, 0, 0);
          ac = __builtin_amdgcn_mfma_f32_16x16x32_bf16(ch, whh_l, ac, 0, 0, 0);
          ac = __builtin_amdgcn_mfma_f32_16x16x32_bf16(cl, whh_h, ac, 0, 0, 0);
        }
        const int t = i - 1;
        #pragma unroll
        for (int j = 0; j < 4; ++j) {
          const int r = drow0 + j;
          float hv = tanhf(acc0[j] + acc1[j]);
          unsigned short hi = f2bf(hv);
          unsigned short lo = f2bf(hv - bf2f(hi));
          stage[0][wid][slotb + j][sjj] = (short)hi;
          stage[1][wid][slotb + j][sjj] = (short)lo;
          out_seq[(size_t)r * S_LEN * HIDDEN + (size_t)t * HIDDEN + ccol] = hv;
          if (i == S_LEN) hidden[32768 + r * HIDDEN + ccol] = hv;  // hidden[1]
        }
        asm volatile("s_waitcnt lgkmcnt(0)" ::: "memory");
        {
          const int l2 = lane & 31, sel = lane >> 5;
          u32x4 v = *(const u32x4*)&stage[sel][wid][l2][0];
          short* dst = (sel ? hL_lo : hL_hi) +
                       (((p * 4 + wid) * 16 + skc) * 64 + sub0 * 16 + l2) * 8;
          st16_sc1(dst, v);
        }
      }
    }

    // device-scope barrier i — RMW-free tag flags, one polling wave per block.
    if (i < S_LEN) {
      asm volatile("s_waitcnt vmcnt(0)" ::: "memory");  // drain sc1 publication + out stores
      __syncthreads();                                  // all waves drained before arrival
      if (tid == 0)
        __hip_atomic_store(&flags[bx * 2], (unsigned)(i + 1),
                           __ATOMIC_RELAXED, __HIP_MEMORY_SCOPE_AGENT);
      if (tid < 64) {                                   // wave 0 polls: lane l watches block l
        for (;;) {
          unsigned f = __hip_atomic_load(&flags[lane * 2],
                                         __ATOMIC_RELAXED, __HIP_MEMORY_SCOPE_AGENT);
          if (__all((int)(f > (unsigned)i))) break;
          __builtin_amdgcn_s_sleep(2);
        }
      }
      __syncthreads();                                  // release other waves
    }
  }
  #undef LOAD_EA
}

extern "C" void kernel_launch(void* const* d_in, const int* in_sizes, int n_in,
                              void* d_out, int out_size, void* d_ws, size_t ws_size,
                              hipStream_t stream) {
  const int*   x    = (const int*)d_in[0];
  // d_in[1] = lengths : unused by the reference
  const float* emb  = (const float*)d_in[2];
  const float* Wih0 = (const float*)d_in[3];
  const float* b0   = (const float*)d_in[4];
  const float* Whh0 = (const float*)d_in[5];
  const float* Wih1 = (const float*)d_in[6];
  const float* b1   = (const float*)d_in[7];
  const float* Whh1 = (const float*)d_in[8];
  float* out = (float*)d_out;

  unsigned* flags = (unsigned*)d_ws;
  short*    hbase = (short*)((char*)d_ws + 1024);

  // re-zero flags + initial h-state every call (ws not re-poisoned between replays;
  // kernel-end flush of k_init makes zeros visible at the coherence point)
  k_init<<<256, 256, 0, stream>>>(flags, (int*)hbase);
  k_rnn<<<NBLK, 256, 0, stream>>>(x, emb, Wih0, b0, Whh0, Wih1, b1, Whh1, out, flags, hbase);
}